// Round 7
// baseline (821.371 us; speedup 1.0000x reference)
//
#include <hip/hip_runtime.h>

// BiLSTM-CRF on MI355X — round 7: zero-streaming lstm_scan.
// kk partition (of 128): 32 in LDS slab (128 KB) | 96 persistent in registers
// (24 uint4/thread x 4 groups; round 6 showed the unified VGPR/AGPR file
// absorbs parked weights at no occupancy cost). No per-step weight stream.
// X4 gate loads software-pipelined 1-deep (issue t+1 before computing t).
//
// ws layout: X4 (67108864 B) | WTH (1048576 B) | FT (786432 B) | H (fp32 33554432
// or bf16 16777216, chosen by ws_size).
// Output (float32): d_out[0:16384] = paths (floats, -1 past length), [16384:16448] = best_score.

#define NB 64
#define NT 256
#define NKTAG 12
#define START_TAG 10
#define KK_RES 32   // kk-pairs resident in LDS -> 128 KiB
#define KK_REG 24   // register-resident kk per thread (kk = 32 + 4r + g)

typedef unsigned short u16;
typedef _Float16 half2v __attribute__((ext_vector_type(2)));

__device__ __forceinline__ float b2f(u16 u) {
  union { unsigned int i; float f; } v; v.i = ((unsigned int)u) << 16; return v.f;
}
__device__ __forceinline__ u16 f2b(float f) {
  union { float f; unsigned int i; } v; v.f = f;
  unsigned int r = v.i + 0x7FFFu + ((v.i >> 16) & 1u);
  return (u16)(r >> 16);
}
__device__ __forceinline__ u16 f2h(float f) {
  union { _Float16 h; u16 u; } v; v.h = (_Float16)f; return v.u;
}
__device__ __forceinline__ float fsig(float x) { return 1.0f / (1.0f + __expf(-x)); }
__device__ __forceinline__ float ftanh(float x) { return 2.0f / (1.0f + __expf(-2.0f * x)) - 1.0f; }

// D = a.lo*b.lo + a.hi*b.hi + c  (v_dot2_f32_f16)
__device__ __forceinline__ float dot2h(unsigned int a, unsigned int b, float c) {
#if __has_builtin(__builtin_amdgcn_fdot2)
  union { unsigned int u; half2v h; } va, vb;
  va.u = a; vb.u = b;
  return __builtin_amdgcn_fdot2(va.h, vb.h, c, false);
#else
  float d;
  asm("v_dot2_f32_f16 %0, %1, %2, %3" : "=v"(d) : "v"(a), "v"(b), "v"(c));
  return d;
#endif
}

// ---------------------------------------------------------------- pack_whh
// WTH[d][kk][j] = uint4 { i:{k0,k1}, f:{k0,k1}, g:{k0,k1}, o:{k0,k1} } as f16
// pairs (k0 = 2kk in low half). Gate rows in Whh: i=j, f=j+256, g=j+512, o=j+768.
__global__ __launch_bounds__(256) void pack_whh(const float* __restrict__ Whf,
                                                const float* __restrict__ Whb,
                                                uint4* __restrict__ WT) {
  int gid = blockIdx.x * 256 + threadIdx.x;      // 2*128*256 = 65536
  int d = gid >> 15;
  int rem = gid & 32767;
  int kk = rem >> 8, j = rem & 255;
  const float* W = d ? Whb : Whf;
  int k0 = kk * 2;
  uint4 o;
  o.x = (unsigned int)f2h(W[(size_t)j * 256 + k0])         | ((unsigned int)f2h(W[(size_t)j * 256 + k0 + 1]) << 16);
  o.y = (unsigned int)f2h(W[(size_t)(j + 256) * 256 + k0]) | ((unsigned int)f2h(W[(size_t)(j + 256) * 256 + k0 + 1]) << 16);
  o.z = (unsigned int)f2h(W[(size_t)(j + 512) * 256 + k0]) | ((unsigned int)f2h(W[(size_t)(j + 512) * 256 + k0 + 1]) << 16);
  o.w = (unsigned int)f2h(W[(size_t)(j + 768) * 256 + k0]) | ((unsigned int)f2h(W[(size_t)(j + 768) * 256 + k0 + 1]) << 16);
  WT[gid] = o;
}

// ---------------------------------------------------------------- gemm_x
// C[i][n] = emb[sent[i]] @ W_all[n]^T + bias[n];  i=(b,t), n=(d,gate,j). fp32.
__global__ __launch_bounds__(256) void gemm_x(const int* __restrict__ sent,
                                              const float* __restrict__ emb,
                                              const float* __restrict__ Wf,
                                              const float* __restrict__ Wb,
                                              const float* __restrict__ bihf,
                                              const float* __restrict__ bhhf,
                                              const float* __restrict__ bihb,
                                              const float* __restrict__ bhhb,
                                              u16* __restrict__ X4) {
  __shared__ float As[16][128];
  __shared__ float Bs[16][64];
  __shared__ int tok[128];
  int tid = threadIdx.x;
  int in = blockIdx.x;   // 0..31
  int im = blockIdx.y;   // 0..127
  if (tid < 128) tok[tid] = sent[im * 128 + tid];
  __syncthreads();
  float acc[8][4];
#pragma unroll
  for (int m = 0; m < 8; ++m)
#pragma unroll
    for (int n = 0; n < 4; ++n) acc[m][n] = 0.f;
  int ty = tid >> 4, tx = tid & 15;
  for (int kt = 0; kt < 16; ++kt) {
    int k0 = kt * 16;
#pragma unroll
    for (int l = 0; l < 2; ++l) {
      int idx = l * 256 + tid;
      int row = idx >> 2, kq = idx & 3;
      const float* ap = emb + (size_t)tok[row] * 256 + k0 + kq * 4;
      float4 av = *(const float4*)ap;
      As[kq * 4 + 0][row] = av.x; As[kq * 4 + 1][row] = av.y;
      As[kq * 4 + 2][row] = av.z; As[kq * 4 + 3][row] = av.w;
    }
    {
      int nrow = tid >> 2, kq = tid & 3;
      int ng = in * 64 + nrow;
      const float* wrow = (ng < 1024) ? (Wf + (size_t)ng * 256) : (Wb + (size_t)(ng - 1024) * 256);
      float4 bv = *(const float4*)(wrow + k0 + kq * 4);
      Bs[kq * 4 + 0][nrow] = bv.x; Bs[kq * 4 + 1][nrow] = bv.y;
      Bs[kq * 4 + 2][nrow] = bv.z; Bs[kq * 4 + 3][nrow] = bv.w;
    }
    __syncthreads();
#pragma unroll
    for (int k = 0; k < 16; ++k) {
      float4 a0 = *(const float4*)&As[k][ty * 8];
      float4 a1 = *(const float4*)&As[k][ty * 8 + 4];
      float4 bb = *(const float4*)&Bs[k][tx * 4];
      float am[8] = {a0.x, a0.y, a0.z, a0.w, a1.x, a1.y, a1.z, a1.w};
      float bn[4] = {bb.x, bb.y, bb.z, bb.w};
#pragma unroll
      for (int m = 0; m < 8; ++m)
#pragma unroll
        for (int n = 0; n < 4; ++n) acc[m][n] += am[m] * bn[n];
    }
    __syncthreads();
  }
#pragma unroll
  for (int n = 0; n < 4; ++n) {
    int ng = in * 64 + tx * 4 + n;
    int d = ng >> 10, r = ng & 1023;
    int g = r >> 8, j = r & 255;
    float bias = d ? (bihb[r] + bhhb[r]) : (bihf[r] + bhhf[r]);
#pragma unroll
    for (int m = 0; m < 8; ++m) {
      int i = im * 128 + ty * 8 + m;
      int bb_ = i >> 8, tt = i & 255;
      size_t o = ((((size_t)d * NT + tt) * NB + bb_) * 256 + j) * 4 + g;
      X4[o] = f2b(acc[m][n] + bias);
    }
  }
}

// ---------------------------------------------------------------- lstm_scan
// One block per (dir d, batch b), 1024 threads = (jj 0..255, group g 0..3).
// Group g per step: 8 LDS-slab kk (g*8+r), 24 register kk (32+4r+g; persistent
// uint4 wreg[24], loaded once, static-indexed). Zero global weight traffic.
// X4 gate load pipelined 1-deep. h packed f16 pairs in LDS. Partials via LDS;
// g0 owns c/gates.
__global__ __launch_bounds__(1024, 4) void lstm_scan(const uint4* __restrict__ WT,
                                                     const ushort4* __restrict__ X4,
                                                     const float* __restrict__ h0,
                                                     const float* __restrict__ c0,
                                                     void* __restrict__ H, int h32) {
  int d = blockIdx.x >> 6, b = blockIdx.x & 63;
  int tid = threadIdx.x;
  int jj = tid & 255, g = tid >> 8;          // g in 0..3
  __shared__ uint4 wlds[KK_RES * 256];       // 131072 B resident weight slab
  __shared__ unsigned int h2s[128];          // packed f16 h pairs
  __shared__ float4 plds[3][256];            // 12288 B partials
  const uint4* Ws = WT + (size_t)d * 32768;  // [kk][jj], 128 x 256 entries
  for (int e = tid; e < KK_RES * 256; e += 1024) wlds[e] = Ws[e];
  // persistent register weights: kk = 32 + 4r + g  (static unroll, rule #20)
  uint4 wreg[KK_REG];
#pragma unroll
  for (int r = 0; r < KK_REG; ++r)
    wreg[r] = Ws[(size_t)(KK_RES + (r << 2) + g) * 256 + jj];
  float c = 0.f;
  if (g == 0) c = c0[((size_t)d * NB + b) * 256 + jj];
  if (tid < 256) ((u16*)h2s)[tid] = f2h(h0[((size_t)d * NB + b) * 256 + tid]);
  // X4 pipeline: offset(t) = xc0 + t*16384
  const size_t xc0 = ((size_t)d * NT * NB + b) * 256 + jj;
  ushort4 xg_next = make_ushort4(0, 0, 0, 0);
  if (g == 0) xg_next = X4[xc0 + (size_t)(d ? NT - 1 : 0) * (NB * 256)];
  __syncthreads();
  for (int s = 0; s < NT; ++s) {
    int t = d ? (NT - 1 - s) : s;
    float ai, af, ag, ao;
    ushort4 xg = xg_next;
    if (g == 0) {
      if (s + 1 < NT) {
        int tn = d ? (NT - 2 - s) : s + 1;
        xg_next = X4[xc0 + (size_t)tn * (NB * 256)];  // issued now, used next step
      }
      ai = b2f(xg.x); af = b2f(xg.y); ag = b2f(xg.z); ao = b2f(xg.w);
    } else {
      ai = af = ag = ao = 0.f;
    }
    // LDS-resident slab: 8 kk per group
#pragma unroll
    for (int r = 0; r < 8; ++r) {
      int kk = g * 8 + r;
      uint4 wv = wlds[(kk << 8) | jj];
      unsigned int hp = h2s[kk];           // wave-uniform -> broadcast
      ai = dot2h(wv.x, hp, ai); af = dot2h(wv.y, hp, af);
      ag = dot2h(wv.z, hp, ag); ao = dot2h(wv.w, hp, ao);
    }
    // register-resident region: 24 kk per thread
#pragma unroll
    for (int r = 0; r < KK_REG; ++r) {
      int kk = KK_RES + (r << 2) + g;
      uint4 wv = wreg[r];
      unsigned int hp = h2s[kk];
      ai = dot2h(wv.x, hp, ai); af = dot2h(wv.y, hp, af);
      ag = dot2h(wv.z, hp, ag); ao = dot2h(wv.w, hp, ao);
    }
    if (g) plds[g - 1][jj] = make_float4(ai, af, ag, ao);
    __syncthreads();    // partials visible; all h2s reads for this step done
    if (g == 0) {
      float4 p0 = plds[0][jj], p1 = plds[1][jj], p2 = plds[2][jj];
      ai += p0.x + p1.x + p2.x;
      af += p0.y + p1.y + p2.y;
      ag += p0.z + p1.z + p2.z;
      ao += p0.w + p1.w + p2.w;
      float ii = fsig(ai), ff = fsig(af), gg = ftanh(ag), oo = fsig(ao);
      c = ff * c + ii * gg;
      float h = oo * ftanh(c);
      ((u16*)h2s)[jj] = f2h(h);
      size_t ho = (((size_t)d * NB + b) * NT + t) * 256 + jj;
      if (h32) ((float*)H)[ho] = h; else ((u16*)H)[ho] = f2b(h);
    }
    __syncthreads();    // h2s updated before next step reads
  }
}

// ---------------------------------------------------------------- feats
// feats[b][t][k] = sum_j hf*Wp[k][j] + hb*Wp[k][256+j] + bp[k]
__global__ __launch_bounds__(384) void feats_kernel(const void* __restrict__ H, int h32,
                                                    const float* __restrict__ Wp,
                                                    const float* __restrict__ bp,
                                                    float* __restrict__ FT) {
  __shared__ float hbuf[32][516];
  int tid = threadIdx.x;
  int i0 = blockIdx.x * 32;
  for (int idx = tid; idx < 32 * 512; idx += 384) {
    int row = idx >> 9, col = idx & 511;
    int i = i0 + row;
    int b = i >> 8, t = i & 255;
    int dd = col >> 8, jj = col & 255;
    size_t ho = (((size_t)dd * NB + b) * NT + t) * 256 + jj;
    hbuf[row][col] = h32 ? ((const float*)H)[ho] : b2f(((const u16*)H)[ho]);
  }
  __syncthreads();
  int row = tid / 12, k = tid - row * 12;  // 384 = 32*12
  const float* wp = Wp + (size_t)k * 512;
  float s = 0.f;
  for (int ccol = 0; ccol < 512; ++ccol) s += hbuf[row][ccol] * wp[ccol];
  int i = i0 + row;
  FT[(size_t)i * NKTAG + k] = s + bp[k];
}

// ---------------------------------------------------------------- viterbi
__global__ __launch_bounds__(64) void viterbi_kernel(const float* __restrict__ FT,
                                                     const float* __restrict__ trans,
                                                     const int* __restrict__ sent,
                                                     float* __restrict__ out) {
  int b = blockIdx.x, tid = threadIdx.x;
  __shared__ float trans_s[12][12];
  __shared__ float s_s[12];
  __shared__ unsigned char bp_s[256][12];
  __shared__ int path_s[256];
  for (int idx = tid; idx < 144; idx += 64) trans_s[idx / 12][idx % 12] = trans[idx];
  int cnt = 0;
#pragma unroll
  for (int q = 0; q < 4; ++q) cnt += (sent[b * NT + q * 64 + tid] > 0) ? 1 : 0;
  for (int off = 32; off; off >>= 1) cnt += __shfl_down(cnt, off);
  int len = __shfl(cnt, 0);
  if (tid < 12) s_s[tid] = (tid == START_TAG) ? 0.f : -10000.f;
  __syncthreads();
  for (int t = 0; t < NT; ++t) {
    float best = 0.f, f = 0.f;
    int barg = 0;
    if (tid < 12) {
      f = FT[((size_t)b * NT + t) * NKTAG + tid];
      best = s_s[0] + trans_s[tid][0];
      barg = 0;
#pragma unroll
      for (int fr = 1; fr < 12; ++fr) {
        float v = s_s[fr] + trans_s[tid][fr];
        if (v > best) { best = v; barg = fr; }  // strict > keeps first (jnp.argmax)
      }
    }
    __syncthreads();
    if (tid < 12) {
      s_s[tid] = best + f;
      bp_s[t][tid] = (unsigned char)barg;
    }
    __syncthreads();
  }
  if (tid == 0) {
    float bs = s_s[0];
    int bt = 0;
    for (int k = 1; k < 12; ++k)
      if (s_s[k] > bs) { bs = s_s[k]; bt = k; }
    out[NB * NT + b] = bs;  // best_score
    int x = bt;
    for (int tt = NT - 1; tt >= 0; --tt) {
      path_s[tt] = x;                  // emit BEFORE stepping back (ref semantics)
      int nxt = bp_s[tt][x];
      if (tt < len) x = nxt;
    }
  }
  __syncthreads();
#pragma unroll
  for (int q = 0; q < 4; ++q) {
    int t = q * 64 + tid;
    out[b * NT + t] = (t < len) ? (float)path_s[t] : -1.0f;
  }
}

// ---------------------------------------------------------------- launch
extern "C" void kernel_launch(void* const* d_in, const int* in_sizes, int n_in,
                              void* d_out, int out_size, void* d_ws, size_t ws_size,
                              hipStream_t stream) {
  (void)in_sizes; (void)n_in; (void)out_size;
  const int*   sent  = (const int*)d_in[0];
  const float* emb   = (const float*)d_in[2];
  const float* Wih_f = (const float*)d_in[3];
  const float* Whh_f = (const float*)d_in[4];
  const float* bih_f = (const float*)d_in[5];
  const float* bhh_f = (const float*)d_in[6];
  const float* Wih_b = (const float*)d_in[7];
  const float* Whh_b = (const float*)d_in[8];
  const float* bih_b = (const float*)d_in[9];
  const float* bhh_b = (const float*)d_in[10];
  const float* Wp    = (const float*)d_in[11];
  const float* bp    = (const float*)d_in[12];
  const float* trans = (const float*)d_in[13];
  const float* h0    = (const float*)d_in[14];
  const float* c0    = (const float*)d_in[15];
  float* out = (float*)d_out;

  char* w = (char*)d_ws;
  u16*   X4  = (u16*)w;                                   // 67108864 B
  uint4* WTH = (uint4*)(w + 67108864);                    //  1048576 B
  float* FT  = (float*)(w + 67108864 + 1048576);          //   786432 B
  void*  H   = (void*)(w + 67108864 + 1048576 + 786432);  // fp32 33554432 or bf16 16777216
  const size_t base = 67108864 + 1048576 + 786432;
  int h32 = (ws_size >= base + (size_t)33554432) ? 1 : 0;

  pack_whh<<<dim3(256), dim3(256), 0, stream>>>(Whh_f, Whh_b, WTH);
  gemm_x<<<dim3(32, 128), dim3(256), 0, stream>>>(sent, emb, Wih_f, Wih_b,
                                                  bih_f, bhh_f, bih_b, bhh_b, X4);
  lstm_scan<<<dim3(128), dim3(1024), 0, stream>>>(WTH, (const ushort4*)X4, h0, c0, H, h32);
  feats_kernel<<<dim3(512), dim3(384), 0, stream>>>(H, h32, Wp, bp, FT);
  viterbi_kernel<<<dim3(64), dim3(64), 0, stream>>>(FT, trans, sent, out);
}

// Round 8
// 769.480 us; speedup vs baseline: 1.0674x; 1.0674x over previous
//
#include <hip/hip_runtime.h>

// BiLSTM-CRF on MI355X — round 8: LDS-issue fix in lstm_scan + dot2 gemm_x.
// R7 lesson: reg cap = 128/thread at 4 waves/SIMD (KK_REG=16 is the max);
// scan was LDS-issue-bound: 32 uniform b32 h-reads/thread/step (~2560 cy).
// Fix: contiguous-per-group kk so h reads become 8 uniform b128 (~500 cy);
// X4 gate term added at END of step (load latency hidden under dot2 work).
// gemm_x: LDS tiles as packed-f16 dwords, inner loop v_dot2 (VALU+LDS halved).
//
// kk partition (128 total): slab kk[0,32) in LDS | regs kk = 32+g*16+r |
// streamed kk = 96+g*8+u (one 128 KB contiguous block window per step).
//
// ws layout: X4 (67108864 B) | WTH (1048576 B) | FT (786432 B) | H (fp32 33554432
// or bf16 16777216, chosen by ws_size).
// Output (float32): d_out[0:16384] = paths (floats, -1 past length), [16384:16448] = best_score.

#define NB 64
#define NT 256
#define NKTAG 12
#define START_TAG 10
#define KK_SLAB 32  // kk in LDS slab -> 128 KiB
#define KK_REG 16   // register-resident kk per thread (kk = 32 + g*16 + r)
#define KK_STRM 8   // streamed kk per thread (kk = 96 + g*8 + u)

typedef unsigned short u16;
typedef _Float16 half2v __attribute__((ext_vector_type(2)));

__device__ __forceinline__ float b2f(u16 u) {
  union { unsigned int i; float f; } v; v.i = ((unsigned int)u) << 16; return v.f;
}
__device__ __forceinline__ u16 f2b(float f) {
  union { float f; unsigned int i; } v; v.f = f;
  unsigned int r = v.i + 0x7FFFu + ((v.i >> 16) & 1u);
  return (u16)(r >> 16);
}
__device__ __forceinline__ u16 f2h(float f) {
  union { _Float16 h; u16 u; } v; v.h = (_Float16)f; return v.u;
}
__device__ __forceinline__ unsigned int pkh(float x, float y) {
  return (unsigned int)f2h(x) | ((unsigned int)f2h(y) << 16);
}
__device__ __forceinline__ float fsig(float x) { return 1.0f / (1.0f + __expf(-x)); }
__device__ __forceinline__ float ftanh(float x) { return 2.0f / (1.0f + __expf(-2.0f * x)) - 1.0f; }

// D = a.lo*b.lo + a.hi*b.hi + c  (v_dot2_f32_f16)
__device__ __forceinline__ float dot2h(unsigned int a, unsigned int b, float c) {
#if __has_builtin(__builtin_amdgcn_fdot2)
  union { unsigned int u; half2v h; } va, vb;
  va.u = a; vb.u = b;
  return __builtin_amdgcn_fdot2(va.h, vb.h, c, false);
#else
  float d;
  asm("v_dot2_f32_f16 %0, %1, %2, %3" : "=v"(d) : "v"(a), "v"(b), "v"(c));
  return d;
#endif
}

// ---------------------------------------------------------------- pack_whh
// WTH[d][kk][j] = uint4 { i:{k0,k1}, f:{k0,k1}, g:{k0,k1}, o:{k0,k1} } as f16
// pairs (k0 = 2kk in low half). Gate rows in Whh: i=j, f=j+256, g=j+512, o=j+768.
__global__ __launch_bounds__(256) void pack_whh(const float* __restrict__ Whf,
                                                const float* __restrict__ Whb,
                                                uint4* __restrict__ WT) {
  int gid = blockIdx.x * 256 + threadIdx.x;      // 2*128*256 = 65536
  int d = gid >> 15;
  int rem = gid & 32767;
  int kk = rem >> 8, j = rem & 255;
  const float* W = d ? Whb : Whf;
  int k0 = kk * 2;
  uint4 o;
  o.x = pkh(W[(size_t)j * 256 + k0],         W[(size_t)j * 256 + k0 + 1]);
  o.y = pkh(W[(size_t)(j + 256) * 256 + k0], W[(size_t)(j + 256) * 256 + k0 + 1]);
  o.z = pkh(W[(size_t)(j + 512) * 256 + k0], W[(size_t)(j + 512) * 256 + k0 + 1]);
  o.w = pkh(W[(size_t)(j + 768) * 256 + k0], W[(size_t)(j + 768) * 256 + k0 + 1]);
  WT[gid] = o;
}

// ---------------------------------------------------------------- gemm_x
// C[i][n] = emb[sent[i]] @ W_all[n]^T + bias[n];  i=(b,t), n=(d,gate,j).
// f16-pair LDS tiles + v_dot2 inner loop, fp32 accumulate.
__global__ __launch_bounds__(256) void gemm_x(const int* __restrict__ sent,
                                              const float* __restrict__ emb,
                                              const float* __restrict__ Wf,
                                              const float* __restrict__ Wb,
                                              const float* __restrict__ bihf,
                                              const float* __restrict__ bhhf,
                                              const float* __restrict__ bihb,
                                              const float* __restrict__ bhhb,
                                              u16* __restrict__ X4) {
  __shared__ unsigned int Ash[8][128];   // [kk][row] packed f16 {2k, 2k+1}
  __shared__ unsigned int Bsh[8][64];    // [kk][col]
  __shared__ int tok[128];
  int tid = threadIdx.x;
  int in = blockIdx.x;   // 0..31
  int im = blockIdx.y;   // 0..127
  if (tid < 128) tok[tid] = sent[im * 128 + tid];
  __syncthreads();
  float acc[8][4];
#pragma unroll
  for (int m = 0; m < 8; ++m)
#pragma unroll
    for (int n = 0; n < 4; ++n) acc[m][n] = 0.f;
  int ty = tid >> 4, tx = tid & 15;
  for (int kt = 0; kt < 16; ++kt) {
    int k0 = kt * 16;
#pragma unroll
    for (int l = 0; l < 2; ++l) {
      int idx = l * 256 + tid;
      int row = idx >> 2, kq = idx & 3;
      const float* ap = emb + (size_t)tok[row] * 256 + k0 + kq * 4;
      float4 av = *(const float4*)ap;
      Ash[kq * 2][row]     = pkh(av.x, av.y);
      Ash[kq * 2 + 1][row] = pkh(av.z, av.w);
    }
    {
      int nrow = tid >> 2, kq = tid & 3;
      int ng = in * 64 + nrow;
      const float* wrow = (ng < 1024) ? (Wf + (size_t)ng * 256) : (Wb + (size_t)(ng - 1024) * 256);
      float4 bv = *(const float4*)(wrow + k0 + kq * 4);
      Bsh[kq * 2][nrow]     = pkh(bv.x, bv.y);
      Bsh[kq * 2 + 1][nrow] = pkh(bv.z, bv.w);
    }
    __syncthreads();
#pragma unroll
    for (int kk2 = 0; kk2 < 8; ++kk2) {
      uint4 a0 = *(const uint4*)&Ash[kk2][ty * 8];
      uint4 a1 = *(const uint4*)&Ash[kk2][ty * 8 + 4];
      uint4 bb = *(const uint4*)&Bsh[kk2][tx * 4];
      unsigned int am[8] = {a0.x, a0.y, a0.z, a0.w, a1.x, a1.y, a1.z, a1.w};
      unsigned int bn[4] = {bb.x, bb.y, bb.z, bb.w};
#pragma unroll
      for (int m = 0; m < 8; ++m)
#pragma unroll
        for (int n = 0; n < 4; ++n) acc[m][n] = dot2h(am[m], bn[n], acc[m][n]);
    }
    __syncthreads();
  }
#pragma unroll
  for (int n = 0; n < 4; ++n) {
    int ng = in * 64 + tx * 4 + n;
    int d = ng >> 10, r = ng & 1023;
    int g = r >> 8, j = r & 255;
    float bias = d ? (bihb[r] + bhhb[r]) : (bihf[r] + bhhf[r]);
#pragma unroll
    for (int m = 0; m < 8; ++m) {
      int i = im * 128 + ty * 8 + m;
      int bb_ = i >> 8, tt = i & 255;
      size_t o = ((((size_t)d * NT + tt) * NB + bb_) * 256 + j) * 4 + g;
      X4[o] = f2b(acc[m][n] + bias);
    }
  }
}

// ---------------------------------------------------------------- lstm_scan
// One block per (dir d, batch b), 1024 threads = (jj 0..255, group g 0..3).
// Per group/step: 8 streamed kk (96+g*8+u, contiguous block window),
// 8 slab kk (g*8+r, LDS), 16 register kk (32+g*16+r, persistent, at the
// 128-reg/4-wave cap). h as packed-f16 pairs read via 8 uniform b128.
// X4 gate term added at END (load latency hidden). Partials via LDS; g0
// owns c/gates.
__global__ __launch_bounds__(1024, 4) void lstm_scan(const uint4* __restrict__ WT,
                                                     const ushort4* __restrict__ X4,
                                                     const float* __restrict__ h0,
                                                     const float* __restrict__ c0,
                                                     void* __restrict__ H, int h32) {
  int d = blockIdx.x >> 6, b = blockIdx.x & 63;
  int tid = threadIdx.x;
  int jj = tid & 255, g = tid >> 8;          // g in 0..3
  __shared__ uint4 wlds[KK_SLAB * 256];      // 131072 B resident weight slab
  __shared__ uint4 h2s4[32];                 // 128 packed f16 h pairs (16B-aligned)
  __shared__ float4 plds[3][256];            // 12288 B partials
  const uint4* Ws = WT + (size_t)d * 32768;  // [kk][jj], 128 x 256 entries
  for (int e = tid; e < KK_SLAB * 256; e += 1024) wlds[e] = Ws[e];
  // persistent register weights: kk = 32 + g*16 + r (contiguous per group)
  uint4 wreg[KK_REG];
#pragma unroll
  for (int r = 0; r < KK_REG; ++r)
    wreg[r] = Ws[(size_t)(KK_SLAB + g * KK_REG + r) * 256 + jj];
  float c = 0.f;
  if (g == 0) c = c0[((size_t)d * NB + b) * 256 + jj];
  if (tid < 256) ((u16*)h2s4)[tid] = f2h(h0[((size_t)d * NB + b) * 256 + tid]);
  __syncthreads();
  for (int s = 0; s < NT; ++s) {
    int t = d ? (NT - 1 - s) : s;
    ushort4 xg = make_ushort4(0, 0, 0, 0);
    if (g == 0) xg = X4[(((size_t)d * NT + t) * NB + b) * 256 + jj];  // used at end
    float ai = 0.f, af = 0.f, ag = 0.f, ao = 0.f;
    // streamed region: kk = 96+g*8+u; h dwords 96+g*8.. = uint4 idx 24+g*2
    {
      uint4 hc0 = h2s4[24 + g * 2], hc1 = h2s4[24 + g * 2 + 1];
      unsigned int hp[8] = {hc0.x, hc0.y, hc0.z, hc0.w, hc1.x, hc1.y, hc1.z, hc1.w};
      const uint4* Wp_ = Ws + (size_t)(96 + g * 8) * 256 + jj;
#pragma unroll
      for (int u = 0; u < KK_STRM; ++u) {
        uint4 wv = Wp_[(size_t)u * 256];
        ai = dot2h(wv.x, hp[u], ai); af = dot2h(wv.y, hp[u], af);
        ag = dot2h(wv.z, hp[u], ag); ao = dot2h(wv.w, hp[u], ao);
      }
    }
    // LDS slab: kk = g*8+r; h dwords g*8.. = uint4 idx g*2
    {
      uint4 ha0 = h2s4[g * 2], ha1 = h2s4[g * 2 + 1];
      unsigned int hp[8] = {ha0.x, ha0.y, ha0.z, ha0.w, ha1.x, ha1.y, ha1.z, ha1.w};
#pragma unroll
      for (int r = 0; r < 8; ++r) {
        uint4 wv = wlds[((g * 8 + r) << 8) | jj];
        ai = dot2h(wv.x, hp[r], ai); af = dot2h(wv.y, hp[r], af);
        ag = dot2h(wv.z, hp[r], ag); ao = dot2h(wv.w, hp[r], ao);
      }
    }
    // register region: kk = 32+g*16+r; h dwords 32+g*16.. = uint4 idx 8+g*4
    {
      uint4 hb0 = h2s4[8 + g * 4], hb1 = h2s4[8 + g * 4 + 1];
      uint4 hb2 = h2s4[8 + g * 4 + 2], hb3 = h2s4[8 + g * 4 + 3];
      unsigned int hp[16] = {hb0.x, hb0.y, hb0.z, hb0.w, hb1.x, hb1.y, hb1.z, hb1.w,
                             hb2.x, hb2.y, hb2.z, hb2.w, hb3.x, hb3.y, hb3.z, hb3.w};
#pragma unroll
      for (int r = 0; r < KK_REG; ++r) {
        uint4 wv = wreg[r];
        ai = dot2h(wv.x, hp[r], ai); af = dot2h(wv.y, hp[r], af);
        ag = dot2h(wv.z, hp[r], ag); ao = dot2h(wv.w, hp[r], ao);
      }
    }
    if (g) plds[g - 1][jj] = make_float4(ai, af, ag, ao);
    __syncthreads();    // partials visible; all h2s4 reads for this step done
    if (g == 0) {
      float4 p0 = plds[0][jj], p1 = plds[1][jj], p2 = plds[2][jj];
      ai += p0.x + p1.x + p2.x + b2f(xg.x);
      af += p0.y + p1.y + p2.y + b2f(xg.y);
      ag += p0.z + p1.z + p2.z + b2f(xg.z);
      ao += p0.w + p1.w + p2.w + b2f(xg.w);
      float ii = fsig(ai), ff = fsig(af), gg = ftanh(ag), oo = fsig(ao);
      c = ff * c + ii * gg;
      float h = oo * ftanh(c);
      ((u16*)h2s4)[jj] = f2h(h);
      size_t ho = (((size_t)d * NB + b) * NT + t) * 256 + jj;
      if (h32) ((float*)H)[ho] = h; else ((u16*)H)[ho] = f2b(h);
    }
    __syncthreads();    // h2s4 updated before next step reads
  }
}

// ---------------------------------------------------------------- feats
// feats[b][t][k] = sum_j hf*Wp[k][j] + hb*Wp[k][256+j] + bp[k]
__global__ __launch_bounds__(384) void feats_kernel(const void* __restrict__ H, int h32,
                                                    const float* __restrict__ Wp,
                                                    const float* __restrict__ bp,
                                                    float* __restrict__ FT) {
  __shared__ float hbuf[32][516];
  int tid = threadIdx.x;
  int i0 = blockIdx.x * 32;
  for (int idx = tid; idx < 32 * 512; idx += 384) {
    int row = idx >> 9, col = idx & 511;
    int i = i0 + row;
    int b = i >> 8, t = i & 255;
    int dd = col >> 8, jj = col & 255;
    size_t ho = (((size_t)dd * NB + b) * NT + t) * 256 + jj;
    hbuf[row][col] = h32 ? ((const float*)H)[ho] : b2f(((const u16*)H)[ho]);
  }
  __syncthreads();
  int row = tid / 12, k = tid - row * 12;  // 384 = 32*12
  const float* wp = Wp + (size_t)k * 512;
  float s = 0.f;
  for (int ccol = 0; ccol < 512; ++ccol) s += hbuf[row][ccol] * wp[ccol];
  int i = i0 + row;
  FT[(size_t)i * NKTAG + k] = s + bp[k];
}

// ---------------------------------------------------------------- viterbi
__global__ __launch_bounds__(64) void viterbi_kernel(const float* __restrict__ FT,
                                                     const float* __restrict__ trans,
                                                     const int* __restrict__ sent,
                                                     float* __restrict__ out) {
  int b = blockIdx.x, tid = threadIdx.x;
  __shared__ float trans_s[12][12];
  __shared__ float s_s[12];
  __shared__ unsigned char bp_s[256][12];
  __shared__ int path_s[256];
  for (int idx = tid; idx < 144; idx += 64) trans_s[idx / 12][idx % 12] = trans[idx];
  int cnt = 0;
#pragma unroll
  for (int q = 0; q < 4; ++q) cnt += (sent[b * NT + q * 64 + tid] > 0) ? 1 : 0;
  for (int off = 32; off; off >>= 1) cnt += __shfl_down(cnt, off);
  int len = __shfl(cnt, 0);
  if (tid < 12) s_s[tid] = (tid == START_TAG) ? 0.f : -10000.f;
  __syncthreads();
  for (int t = 0; t < NT; ++t) {
    float best = 0.f, f = 0.f;
    int barg = 0;
    if (tid < 12) {
      f = FT[((size_t)b * NT + t) * NKTAG + tid];
      best = s_s[0] + trans_s[tid][0];
      barg = 0;
#pragma unroll
      for (int fr = 1; fr < 12; ++fr) {
        float v = s_s[fr] + trans_s[tid][fr];
        if (v > best) { best = v; barg = fr; }  // strict > keeps first (jnp.argmax)
      }
    }
    __syncthreads();
    if (tid < 12) {
      s_s[tid] = best + f;
      bp_s[t][tid] = (unsigned char)barg;
    }
    __syncthreads();
  }
  if (tid == 0) {
    float bs = s_s[0];
    int bt = 0;
    for (int k = 1; k < 12; ++k)
      if (s_s[k] > bs) { bs = s_s[k]; bt = k; }
    out[NB * NT + b] = bs;  // best_score
    int x = bt;
    for (int tt = NT - 1; tt >= 0; --tt) {
      path_s[tt] = x;                  // emit BEFORE stepping back (ref semantics)
      int nxt = bp_s[tt][x];
      if (tt < len) x = nxt;
    }
  }
  __syncthreads();
#pragma unroll
  for (int q = 0; q < 4; ++q) {
    int t = q * 64 + tid;
    out[b * NT + t] = (t < len) ? (float)path_s[t] : -1.0f;
  }
}

// ---------------------------------------------------------------- launch
extern "C" void kernel_launch(void* const* d_in, const int* in_sizes, int n_in,
                              void* d_out, int out_size, void* d_ws, size_t ws_size,
                              hipStream_t stream) {
  (void)in_sizes; (void)n_in; (void)out_size;
  const int*   sent  = (const int*)d_in[0];
  const float* emb   = (const float*)d_in[2];
  const float* Wih_f = (const float*)d_in[3];
  const float* Whh_f = (const float*)d_in[4];
  const float* bih_f = (const float*)d_in[5];
  const float* bhh_f = (const float*)d_in[6];
  const float* Wih_b = (const float*)d_in[7];
  const float* Whh_b = (const float*)d_in[8];
  const float* bih_b = (const float*)d_in[9];
  const float* bhh_b = (const float*)d_in[10];
  const float* Wp    = (const float*)d_in[11];
  const float* bp    = (const float*)d_in[12];
  const float* trans = (const float*)d_in[13];
  const float* h0    = (const float*)d_in[14];
  const float* c0    = (const float*)d_in[15];
  float* out = (float*)d_out;

  char* w = (char*)d_ws;
  u16*   X4  = (u16*)w;                                   // 67108864 B
  uint4* WTH = (uint4*)(w + 67108864);                    //  1048576 B
  float* FT  = (float*)(w + 67108864 + 1048576);          //   786432 B
  void*  H   = (void*)(w + 67108864 + 1048576 + 786432);  // fp32 33554432 or bf16 16777216
  const size_t base = 67108864 + 1048576 + 786432;
  int h32 = (ws_size >= base + (size_t)33554432) ? 1 : 0;

  pack_whh<<<dim3(256), dim3(256), 0, stream>>>(Whh_f, Whh_b, WTH);
  gemm_x<<<dim3(32, 128), dim3(256), 0, stream>>>(sent, emb, Wih_f, Wih_b,
                                                  bih_f, bhh_f, bih_b, bhh_b, X4);
  lstm_scan<<<dim3(128), dim3(1024), 0, stream>>>(WTH, (const ushort4*)X4, h0, c0, H, h32);
  feats_kernel<<<dim3(512), dim3(384), 0, stream>>>(H, h32, Wp, bp, FT);
  viterbi_kernel<<<dim3(64), dim3(64), 0, stream>>>(FT, trans, sent, out);
}

// Round 9
// 658.761 us; speedup vs baseline: 1.2468x; 1.1681x over previous
//
#include <hip/hip_runtime.h>

// BiLSTM-CRF on MI355X — round 9: MFMA gemm_x. Scan kept byte-identical
// (R8 control; it is LDS/structure-bound at ~455us with half the chip idle
// by decomposition). gemm_x was LDS-issue-bound (384 b128/thread); MFMA
// 16x16x32 f16 cuts it to 6 b128 + 8 MFMA per wave-chunk.
//
// ws layout: X4 (67108864 B) | WTH (1048576 B) | FT (786432 B) | H (fp32 33554432
// or bf16 16777216, chosen by ws_size).
// Output (float32): d_out[0:16384] = paths (floats, -1 past length), [16384:16448] = best_score.

#define NB 64
#define NT 256
#define NKTAG 12
#define START_TAG 10
#define KK_SLAB 32  // kk in LDS slab -> 128 KiB
#define KK_REG 16   // register-resident kk per thread (kk = 32 + g*16 + r)
#define KK_STRM 8   // streamed kk per thread (kk = 96 + g*8 + u)

typedef unsigned short u16;
typedef _Float16 half2v __attribute__((ext_vector_type(2)));
typedef _Float16 half8 __attribute__((ext_vector_type(8)));
typedef float f32x4 __attribute__((ext_vector_type(4)));

__device__ __forceinline__ float b2f(u16 u) {
  union { unsigned int i; float f; } v; v.i = ((unsigned int)u) << 16; return v.f;
}
__device__ __forceinline__ u16 f2b(float f) {
  union { float f; unsigned int i; } v; v.f = f;
  unsigned int r = v.i + 0x7FFFu + ((v.i >> 16) & 1u);
  return (u16)(r >> 16);
}
__device__ __forceinline__ u16 f2h(float f) {
  union { _Float16 h; u16 u; } v; v.h = (_Float16)f; return v.u;
}
__device__ __forceinline__ unsigned int pkh(float x, float y) {
  return (unsigned int)f2h(x) | ((unsigned int)f2h(y) << 16);
}
__device__ __forceinline__ float fsig(float x) { return 1.0f / (1.0f + __expf(-x)); }
__device__ __forceinline__ float ftanh(float x) { return 2.0f / (1.0f + __expf(-2.0f * x)) - 1.0f; }

// D = a.lo*b.lo + a.hi*b.hi + c  (v_dot2_f32_f16)
__device__ __forceinline__ float dot2h(unsigned int a, unsigned int b, float c) {
#if __has_builtin(__builtin_amdgcn_fdot2)
  union { unsigned int u; half2v h; } va, vb;
  va.u = a; vb.u = b;
  return __builtin_amdgcn_fdot2(va.h, vb.h, c, false);
#else
  float d;
  asm("v_dot2_f32_f16 %0, %1, %2, %3" : "=v"(d) : "v"(a), "v"(b), "v"(c));
  return d;
#endif
}

// ---------------------------------------------------------------- pack_whh
// WTH[d][kk][j] = uint4 { i:{k0,k1}, f:{k0,k1}, g:{k0,k1}, o:{k0,k1} } as f16
// pairs (k0 = 2kk in low half). Gate rows in Whh: i=j, f=j+256, g=j+512, o=j+768.
__global__ __launch_bounds__(256) void pack_whh(const float* __restrict__ Whf,
                                                const float* __restrict__ Whb,
                                                uint4* __restrict__ WT) {
  int gid = blockIdx.x * 256 + threadIdx.x;      // 2*128*256 = 65536
  int d = gid >> 15;
  int rem = gid & 32767;
  int kk = rem >> 8, j = rem & 255;
  const float* W = d ? Whb : Whf;
  int k0 = kk * 2;
  uint4 o;
  o.x = pkh(W[(size_t)j * 256 + k0],         W[(size_t)j * 256 + k0 + 1]);
  o.y = pkh(W[(size_t)(j + 256) * 256 + k0], W[(size_t)(j + 256) * 256 + k0 + 1]);
  o.z = pkh(W[(size_t)(j + 512) * 256 + k0], W[(size_t)(j + 512) * 256 + k0 + 1]);
  o.w = pkh(W[(size_t)(j + 768) * 256 + k0], W[(size_t)(j + 768) * 256 + k0 + 1]);
  WT[gid] = o;
}

// ---------------------------------------------------------------- gemm_x (MFMA)
// C[i][n] = emb[sent[i]] @ W_all[n]^T + bias[n];  i=(b,t), n=(d,gate,j).
// 128(M) x 64(N) per block, 4 waves; K = 8 chunks x 32; mfma_f32_16x16x32_f16.
// LDS tiles padded to 40 f16 (80 B rows -> <=2-way bank aliasing, free).
__global__ __launch_bounds__(256) void gemm_x(const int* __restrict__ sent,
                                              const float* __restrict__ emb,
                                              const float* __restrict__ Wf,
                                              const float* __restrict__ Wb,
                                              const float* __restrict__ bihf,
                                              const float* __restrict__ bhhf,
                                              const float* __restrict__ bihb,
                                              const float* __restrict__ bhhb,
                                              u16* __restrict__ X4) {
  __shared__ _Float16 A_lds[128][40];
  __shared__ _Float16 B_lds[64][40];
  __shared__ int tok[128];
  int tid = threadIdx.x;
  int in = blockIdx.x;   // 0..31  (N tiles of 64)
  int im = blockIdx.y;   // 0..127 (M tiles of 128)
  if (tid < 128) tok[tid] = sent[im * 128 + tid];

  int w = tid >> 6, l = tid & 63;
  int lrow = l & 15, lk = l >> 4;      // fragment row/col and k-group
  f32x4 acc[2][4];
#pragma unroll
  for (int mt = 0; mt < 2; ++mt)
#pragma unroll
    for (int nt = 0; nt < 4; ++nt) acc[mt][nt] = (f32x4)0.0f;

  // staging assignments
  int arow = tid >> 1, akh = tid & 1;          // A: 128 rows x 2 k-halves (16 f32)
  int brow = tid & 63, bkq = tid >> 6;         // B: 64 rows x 4 k-quads (8 f32)
  int ngb = in * 64 + brow;
  const float* wrow = (ngb < 1024) ? (Wf + (size_t)ngb * 256) : (Wb + (size_t)(ngb - 1024) * 256);

  for (int kc = 0; kc < 8; ++kc) {
    int k0 = kc * 32;
    __syncthreads();   // also covers tok on first iteration
    // stage A: emb rows -> f16, each thread 16 f32 (2 x b128 writes)
    {
      const float* ap = emb + (size_t)tok[arow] * 256 + k0 + akh * 16;
#pragma unroll
      for (int q = 0; q < 2; ++q) {
        float4 v0 = *(const float4*)(ap + q * 8);
        float4 v1 = *(const float4*)(ap + q * 8 + 4);
        uint4 pk;
        pk.x = pkh(v0.x, v0.y); pk.y = pkh(v0.z, v0.w);
        pk.z = pkh(v1.x, v1.y); pk.w = pkh(v1.z, v1.w);
        *(uint4*)&A_lds[arow][akh * 16 + q * 8] = pk;
      }
    }
    // stage B: W rows -> f16, each thread 8 f32 (1 x b128 write)
    {
      float4 v0 = *(const float4*)(wrow + k0 + bkq * 8);
      float4 v1 = *(const float4*)(wrow + k0 + bkq * 8 + 4);
      uint4 pk;
      pk.x = pkh(v0.x, v0.y); pk.y = pkh(v0.z, v0.w);
      pk.z = pkh(v1.x, v1.y); pk.w = pkh(v1.z, v1.w);
      *(uint4*)&B_lds[brow][bkq * 8] = pk;
    }
    __syncthreads();
    // fragments + MFMA
    half8 af[2], bf[4];
#pragma unroll
    for (int mt = 0; mt < 2; ++mt)
      af[mt] = *(const half8*)&A_lds[w * 32 + mt * 16 + lrow][lk * 8];
#pragma unroll
    for (int nt = 0; nt < 4; ++nt)
      bf[nt] = *(const half8*)&B_lds[nt * 16 + lrow][lk * 8];
#pragma unroll
    for (int mt = 0; mt < 2; ++mt)
#pragma unroll
      for (int nt = 0; nt < 4; ++nt)
        acc[mt][nt] = __builtin_amdgcn_mfma_f32_16x16x32_f16(af[mt], bf[nt], acc[mt][nt], 0, 0, 0);
  }
  // epilogue: bias + bf16 + scatter to X4[d][t][b][j][gate]
#pragma unroll
  for (int nt = 0; nt < 4; ++nt) {
    int n = in * 64 + nt * 16 + lrow;
    int d = n >> 10, rr = n & 1023;
    int gate = rr >> 8, j = rr & 255;
    float bias = d ? (bihb[rr] + bhhb[rr]) : (bihf[rr] + bhhf[rr]);
#pragma unroll
    for (int mt = 0; mt < 2; ++mt) {
#pragma unroll
      for (int r = 0; r < 4; ++r) {
        int i = im * 128 + w * 32 + mt * 16 + lk * 4 + r;
        int bb = i >> 8, tt = i & 255;
        size_t o = ((((size_t)d * NT + tt) * NB + bb) * 256 + j) * 4 + gate;
        X4[o] = f2b(acc[mt][nt][r] + bias);
      }
    }
  }
}

// ---------------------------------------------------------------- lstm_scan
// (unchanged from round 8 — control)
__global__ __launch_bounds__(1024, 4) void lstm_scan(const uint4* __restrict__ WT,
                                                     const ushort4* __restrict__ X4,
                                                     const float* __restrict__ h0,
                                                     const float* __restrict__ c0,
                                                     void* __restrict__ H, int h32) {
  int d = blockIdx.x >> 6, b = blockIdx.x & 63;
  int tid = threadIdx.x;
  int jj = tid & 255, g = tid >> 8;          // g in 0..3
  __shared__ uint4 wlds[KK_SLAB * 256];      // 131072 B resident weight slab
  __shared__ uint4 h2s4[32];                 // 128 packed f16 h pairs (16B-aligned)
  __shared__ float4 plds[3][256];            // 12288 B partials
  const uint4* Ws = WT + (size_t)d * 32768;  // [kk][jj], 128 x 256 entries
  for (int e = tid; e < KK_SLAB * 256; e += 1024) wlds[e] = Ws[e];
  uint4 wreg[KK_REG];
#pragma unroll
  for (int r = 0; r < KK_REG; ++r)
    wreg[r] = Ws[(size_t)(KK_SLAB + g * KK_REG + r) * 256 + jj];
  float c = 0.f;
  if (g == 0) c = c0[((size_t)d * NB + b) * 256 + jj];
  if (tid < 256) ((u16*)h2s4)[tid] = f2h(h0[((size_t)d * NB + b) * 256 + tid]);
  __syncthreads();
  for (int s = 0; s < NT; ++s) {
    int t = d ? (NT - 1 - s) : s;
    ushort4 xg = make_ushort4(0, 0, 0, 0);
    if (g == 0) xg = X4[(((size_t)d * NT + t) * NB + b) * 256 + jj];  // used at end
    float ai = 0.f, af = 0.f, ag = 0.f, ao = 0.f;
    // streamed region: kk = 96+g*8+u
    {
      uint4 hc0 = h2s4[24 + g * 2], hc1 = h2s4[24 + g * 2 + 1];
      unsigned int hp[8] = {hc0.x, hc0.y, hc0.z, hc0.w, hc1.x, hc1.y, hc1.z, hc1.w};
      const uint4* Wp_ = Ws + (size_t)(96 + g * 8) * 256 + jj;
#pragma unroll
      for (int u = 0; u < KK_STRM; ++u) {
        uint4 wv = Wp_[(size_t)u * 256];
        ai = dot2h(wv.x, hp[u], ai); af = dot2h(wv.y, hp[u], af);
        ag = dot2h(wv.z, hp[u], ag); ao = dot2h(wv.w, hp[u], ao);
      }
    }
    // LDS slab: kk = g*8+r
    {
      uint4 ha0 = h2s4[g * 2], ha1 = h2s4[g * 2 + 1];
      unsigned int hp[8] = {ha0.x, ha0.y, ha0.z, ha0.w, ha1.x, ha1.y, ha1.z, ha1.w};
#pragma unroll
      for (int r = 0; r < 8; ++r) {
        uint4 wv = wlds[((g * 8 + r) << 8) | jj];
        ai = dot2h(wv.x, hp[r], ai); af = dot2h(wv.y, hp[r], af);
        ag = dot2h(wv.z, hp[r], ag); ao = dot2h(wv.w, hp[r], ao);
      }
    }
    // register region: kk = 32+g*16+r
    {
      uint4 hb0 = h2s4[8 + g * 4], hb1 = h2s4[8 + g * 4 + 1];
      uint4 hb2 = h2s4[8 + g * 4 + 2], hb3 = h2s4[8 + g * 4 + 3];
      unsigned int hp[16] = {hb0.x, hb0.y, hb0.z, hb0.w, hb1.x, hb1.y, hb1.z, hb1.w,
                             hb2.x, hb2.y, hb2.z, hb2.w, hb3.x, hb3.y, hb3.z, hb3.w};
#pragma unroll
      for (int r = 0; r < KK_REG; ++r) {
        uint4 wv = wreg[r];
        ai = dot2h(wv.x, hp[r], ai); af = dot2h(wv.y, hp[r], af);
        ag = dot2h(wv.z, hp[r], ag); ao = dot2h(wv.w, hp[r], ao);
      }
    }
    if (g) plds[g - 1][jj] = make_float4(ai, af, ag, ao);
    __syncthreads();    // partials visible; all h2s4 reads for this step done
    if (g == 0) {
      float4 p0 = plds[0][jj], p1 = plds[1][jj], p2 = plds[2][jj];
      ai += p0.x + p1.x + p2.x + b2f(xg.x);
      af += p0.y + p1.y + p2.y + b2f(xg.y);
      ag += p0.z + p1.z + p2.z + b2f(xg.z);
      ao += p0.w + p1.w + p2.w + b2f(xg.w);
      float ii = fsig(ai), ff = fsig(af), gg = ftanh(ag), oo = fsig(ao);
      c = ff * c + ii * gg;
      float h = oo * ftanh(c);
      ((u16*)h2s4)[jj] = f2h(h);
      size_t ho = (((size_t)d * NB + b) * NT + t) * 256 + jj;
      if (h32) ((float*)H)[ho] = h; else ((u16*)H)[ho] = f2b(h);
    }
    __syncthreads();    // h2s4 updated before next step reads
  }
}

// ---------------------------------------------------------------- feats
// feats[b][t][k] = sum_j hf*Wp[k][j] + hb*Wp[k][256+j] + bp[k]
__global__ __launch_bounds__(384) void feats_kernel(const void* __restrict__ H, int h32,
                                                    const float* __restrict__ Wp,
                                                    const float* __restrict__ bp,
                                                    float* __restrict__ FT) {
  __shared__ float hbuf[32][516];
  int tid = threadIdx.x;
  int i0 = blockIdx.x * 32;
  for (int idx = tid; idx < 32 * 512; idx += 384) {
    int row = idx >> 9, col = idx & 511;
    int i = i0 + row;
    int b = i >> 8, t = i & 255;
    int dd = col >> 8, jj = col & 255;
    size_t ho = (((size_t)dd * NB + b) * NT + t) * 256 + jj;
    hbuf[row][col] = h32 ? ((const float*)H)[ho] : b2f(((const u16*)H)[ho]);
  }
  __syncthreads();
  int row = tid / 12, k = tid - row * 12;  // 384 = 32*12
  const float* wp = Wp + (size_t)k * 512;
  float s = 0.f;
  for (int ccol = 0; ccol < 512; ++ccol) s += hbuf[row][ccol] * wp[ccol];
  int i = i0 + row;
  FT[(size_t)i * NKTAG + k] = s + bp[k];
}

// ---------------------------------------------------------------- viterbi
__global__ __launch_bounds__(64) void viterbi_kernel(const float* __restrict__ FT,
                                                     const float* __restrict__ trans,
                                                     const int* __restrict__ sent,
                                                     float* __restrict__ out) {
  int b = blockIdx.x, tid = threadIdx.x;
  __shared__ float trans_s[12][12];
  __shared__ float s_s[12];
  __shared__ unsigned char bp_s[256][12];
  __shared__ int path_s[256];
  for (int idx = tid; idx < 144; idx += 64) trans_s[idx / 12][idx % 12] = trans[idx];
  int cnt = 0;
#pragma unroll
  for (int q = 0; q < 4; ++q) cnt += (sent[b * NT + q * 64 + tid] > 0) ? 1 : 0;
  for (int off = 32; off; off >>= 1) cnt += __shfl_down(cnt, off);
  int len = __shfl(cnt, 0);
  if (tid < 12) s_s[tid] = (tid == START_TAG) ? 0.f : -10000.f;
  __syncthreads();
  for (int t = 0; t < NT; ++t) {
    float best = 0.f, f = 0.f;
    int barg = 0;
    if (tid < 12) {
      f = FT[((size_t)b * NT + t) * NKTAG + tid];
      best = s_s[0] + trans_s[tid][0];
      barg = 0;
#pragma unroll
      for (int fr = 1; fr < 12; ++fr) {
        float v = s_s[fr] + trans_s[tid][fr];
        if (v > best) { best = v; barg = fr; }  // strict > keeps first (jnp.argmax)
      }
    }
    __syncthreads();
    if (tid < 12) {
      s_s[tid] = best + f;
      bp_s[t][tid] = (unsigned char)barg;
    }
    __syncthreads();
  }
  if (tid == 0) {
    float bs = s_s[0];
    int bt = 0;
    for (int k = 1; k < 12; ++k)
      if (s_s[k] > bs) { bs = s_s[k]; bt = k; }
    out[NB * NT + b] = bs;  // best_score
    int x = bt;
    for (int tt = NT - 1; tt >= 0; --tt) {
      path_s[tt] = x;                  // emit BEFORE stepping back (ref semantics)
      int nxt = bp_s[tt][x];
      if (tt < len) x = nxt;
    }
  }
  __syncthreads();
#pragma unroll
  for (int q = 0; q < 4; ++q) {
    int t = q * 64 + tid;
    out[b * NT + t] = (t < len) ? (float)path_s[t] : -1.0f;
  }
}

// ---------------------------------------------------------------- launch
extern "C" void kernel_launch(void* const* d_in, const int* in_sizes, int n_in,
                              void* d_out, int out_size, void* d_ws, size_t ws_size,
                              hipStream_t stream) {
  (void)in_sizes; (void)n_in; (void)out_size;
  const int*   sent  = (const int*)d_in[0];
  const float* emb   = (const float*)d_in[2];
  const float* Wih_f = (const float*)d_in[3];
  const float* Whh_f = (const float*)d_in[4];
  const float* bih_f = (const float*)d_in[5];
  const float* bhh_f = (const float*)d_in[6];
  const float* Wih_b = (const float*)d_in[7];
  const float* Whh_b = (const float*)d_in[8];
  const float* bih_b = (const float*)d_in[9];
  const float* bhh_b = (const float*)d_in[10];
  const float* Wp    = (const float*)d_in[11];
  const float* bp    = (const float*)d_in[12];
  const float* trans = (const float*)d_in[13];
  const float* h0    = (const float*)d_in[14];
  const float* c0    = (const float*)d_in[15];
  float* out = (float*)d_out;

  char* w = (char*)d_ws;
  u16*   X4  = (u16*)w;                                   // 67108864 B
  uint4* WTH = (uint4*)(w + 67108864);                    //  1048576 B
  float* FT  = (float*)(w + 67108864 + 1048576);          //   786432 B
  void*  H   = (void*)(w + 67108864 + 1048576 + 786432);  // fp32 33554432 or bf16 16777216
  const size_t base = 67108864 + 1048576 + 786432;
  int h32 = (ws_size >= base + (size_t)33554432) ? 1 : 0;

  pack_whh<<<dim3(256), dim3(256), 0, stream>>>(Whh_f, Whh_b, WTH);
  gemm_x<<<dim3(32, 128), dim3(256), 0, stream>>>(sent, emb, Wih_f, Wih_b,
                                                  bih_f, bhh_f, bih_b, bhh_b, X4);
  lstm_scan<<<dim3(128), dim3(1024), 0, stream>>>(WTH, (const ushort4*)X4, h0, c0, H, h32);
  feats_kernel<<<dim3(512), dim3(384), 0, stream>>>(H, h32, Wp, bp, FT);
  viterbi_kernel<<<dim3(64), dim3(64), 0, stream>>>(FT, trans, sent, out);
}

// Round 10
// 599.398 us; speedup vs baseline: 1.3703x; 1.0990x over previous
//
#include <hip/hip_runtime.h>

// BiLSTM-CRF on MI355X — round 10: non-scan cleanup.
//  * gemm_x: N-tile = 16j x 4gates (d=in>>4, j0=(in&15)*16) + LDS-staged
//    epilogue -> dense 128-B-aligned X4 writes (was 25% line efficiency).
//  * feats: H stored f16; packed-pair uint4 reads + dot2 (LDS instrs /4).
//    Wp pre-packed to f16 pairs (WpH) in pack_whh's extra block.
//  * lstm_scan: byte-identical control except H store = f2h (h32 path dropped).
//
// ws layout: X4 (67108864) | WTH (1048576) | FT (786432) | WpH (12288) |
//            H u16 (16777216)  = 85.7 MB total.
// Output (float32): d_out[0:16384] = paths (floats, -1 past length), [16384:16448] = best_score.

#define NB 64
#define NT 256
#define NKTAG 12
#define START_TAG 10
#define KK_SLAB 32
#define KK_REG 16
#define KK_STRM 8

typedef unsigned short u16;
typedef _Float16 half2v __attribute__((ext_vector_type(2)));
typedef _Float16 half8 __attribute__((ext_vector_type(8)));
typedef float f32x4 __attribute__((ext_vector_type(4)));

__device__ __forceinline__ float b2f(u16 u) {
  union { unsigned int i; float f; } v; v.i = ((unsigned int)u) << 16; return v.f;
}
__device__ __forceinline__ u16 f2b(float f) {
  union { float f; unsigned int i; } v; v.f = f;
  unsigned int r = v.i + 0x7FFFu + ((v.i >> 16) & 1u);
  return (u16)(r >> 16);
}
__device__ __forceinline__ u16 f2h(float f) {
  union { _Float16 h; u16 u; } v; v.h = (_Float16)f; return v.u;
}
__device__ __forceinline__ unsigned int pkh(float x, float y) {
  return (unsigned int)f2h(x) | ((unsigned int)f2h(y) << 16);
}
__device__ __forceinline__ float fsig(float x) { return 1.0f / (1.0f + __expf(-x)); }
__device__ __forceinline__ float ftanh(float x) { return 2.0f / (1.0f + __expf(-2.0f * x)) - 1.0f; }

__device__ __forceinline__ float dot2h(unsigned int a, unsigned int b, float c) {
#if __has_builtin(__builtin_amdgcn_fdot2)
  union { unsigned int u; half2v h; } va, vb;
  va.u = a; vb.u = b;
  return __builtin_amdgcn_fdot2(va.h, vb.h, c, false);
#else
  float d;
  asm("v_dot2_f32_f16 %0, %1, %2, %3" : "=v"(d) : "v"(a), "v"(b), "v"(c));
  return d;
#endif
}

// ---------------------------------------------------------------- pack_whh (+WpH)
__global__ __launch_bounds__(256) void pack_whh(const float* __restrict__ Whf,
                                                const float* __restrict__ Whb,
                                                const float* __restrict__ Wp,
                                                uint4* __restrict__ WT,
                                                unsigned int* __restrict__ WpH) {
  if (blockIdx.x == 256) {   // WpH: [12][256] packed f16 pairs of Wp[12][512]
    for (int it = 0; it < 12; ++it) {
      int idx = it * 256 + threadIdx.x;
      int k = idx >> 8, cc = idx & 255;
      WpH[idx] = pkh(Wp[(size_t)k * 512 + 2 * cc], Wp[(size_t)k * 512 + 2 * cc + 1]);
    }
    return;
  }
  int gid = blockIdx.x * 256 + threadIdx.x;      // 2*128*256 = 65536
  int d = gid >> 15;
  int rem = gid & 32767;
  int kk = rem >> 8, j = rem & 255;
  const float* W = d ? Whb : Whf;
  int k0 = kk * 2;
  uint4 o;
  o.x = pkh(W[(size_t)j * 256 + k0],         W[(size_t)j * 256 + k0 + 1]);
  o.y = pkh(W[(size_t)(j + 256) * 256 + k0], W[(size_t)(j + 256) * 256 + k0 + 1]);
  o.z = pkh(W[(size_t)(j + 512) * 256 + k0], W[(size_t)(j + 512) * 256 + k0 + 1]);
  o.w = pkh(W[(size_t)(j + 768) * 256 + k0], W[(size_t)(j + 768) * 256 + k0 + 1]);
  WT[gid] = o;
}

// ---------------------------------------------------------------- gemm_x (MFMA)
// Block: M=128 (one b, 128 consecutive t), N=64 = 16 j x 4 gates, one dir.
// in: d = in>>4, j0 = (in&15)*16. Epilogue: LDS stage -> dense 128-B X4 rows.
__global__ __launch_bounds__(256) void gemm_x(const int* __restrict__ sent,
                                              const float* __restrict__ emb,
                                              const float* __restrict__ Wf,
                                              const float* __restrict__ Wb,
                                              const float* __restrict__ bihf,
                                              const float* __restrict__ bhhf,
                                              const float* __restrict__ bihb,
                                              const float* __restrict__ bhhb,
                                              u16* __restrict__ X4) {
  __shared__ _Float16 A_lds[128][40];
  __shared__ _Float16 B_lds[64][40];
  __shared__ int tok[128];
  __shared__ u16 Xs[128][80];          // padded to 160 B rows (16-B aligned)
  int tid = threadIdx.x;
  int in = blockIdx.x;                 // 0..31
  int im = blockIdx.y;                 // 0..127
  int d = in >> 4, j0 = (in & 15) * 16;
  if (tid < 128) tok[tid] = sent[im * 128 + tid];

  int w = tid >> 6, l = tid & 63;
  int lrow = l & 15, lk = l >> 4;
  f32x4 acc[2][4];
#pragma unroll
  for (int mt = 0; mt < 2; ++mt)
#pragma unroll
    for (int nt = 0; nt < 4; ++nt) acc[mt][nt] = (f32x4)0.0f;

  int arow = tid >> 1, akh = tid & 1;
  int brow = tid & 63, bkq = tid >> 6;
  int r_w = ((brow >> 4) << 8) + j0 + (brow & 15);   // gate*256 + j
  const float* wrow = (d ? Wb : Wf) + (size_t)r_w * 256;

  for (int kc = 0; kc < 8; ++kc) {
    int k0 = kc * 32;
    __syncthreads();   // covers tok on first iteration
    {
      const float* ap = emb + (size_t)tok[arow] * 256 + k0 + akh * 16;
#pragma unroll
      for (int q = 0; q < 2; ++q) {
        float4 v0 = *(const float4*)(ap + q * 8);
        float4 v1 = *(const float4*)(ap + q * 8 + 4);
        uint4 pk;
        pk.x = pkh(v0.x, v0.y); pk.y = pkh(v0.z, v0.w);
        pk.z = pkh(v1.x, v1.y); pk.w = pkh(v1.z, v1.w);
        *(uint4*)&A_lds[arow][akh * 16 + q * 8] = pk;
      }
    }
    {
      float4 v0 = *(const float4*)(wrow + k0 + bkq * 8);
      float4 v1 = *(const float4*)(wrow + k0 + bkq * 8 + 4);
      uint4 pk;
      pk.x = pkh(v0.x, v0.y); pk.y = pkh(v0.z, v0.w);
      pk.z = pkh(v1.x, v1.y); pk.w = pkh(v1.z, v1.w);
      *(uint4*)&B_lds[brow][bkq * 8] = pk;
    }
    __syncthreads();
    half8 af[2], bf[4];
#pragma unroll
    for (int mt = 0; mt < 2; ++mt)
      af[mt] = *(const half8*)&A_lds[w * 32 + mt * 16 + lrow][lk * 8];
#pragma unroll
    for (int nt = 0; nt < 4; ++nt)
      bf[nt] = *(const half8*)&B_lds[nt * 16 + lrow][lk * 8];
#pragma unroll
    for (int mt = 0; mt < 2; ++mt)
#pragma unroll
      for (int nt = 0; nt < 4; ++nt)
        acc[mt][nt] = __builtin_amdgcn_mfma_f32_16x16x32_f16(af[mt], bf[nt], acc[mt][nt], 0, 0, 0);
  }
  // epilogue: bias, pack 4 gates per (row,j) into b64, stage, dense flush
  float bias[4];
#pragma unroll
  for (int nt = 0; nt < 4; ++nt) {
    int rr = nt * 256 + j0 + lrow;    // gate*256 + j
    bias[nt] = d ? (bihb[rr] + bhhb[rr]) : (bihf[rr] + bhhf[rr]);
  }
  __syncthreads();  // A/B_lds no longer needed; Xs phase
#pragma unroll
  for (int mt = 0; mt < 2; ++mt)
#pragma unroll
    for (int r = 0; r < 4; ++r) {
      int row = w * 32 + mt * 16 + lk * 4 + r;
      uint2 pk;
      pk.x = (unsigned int)f2b(acc[mt][0][r] + bias[0]) |
             ((unsigned int)f2b(acc[mt][1][r] + bias[1]) << 16);
      pk.y = (unsigned int)f2b(acc[mt][2][r] + bias[2]) |
             ((unsigned int)f2b(acc[mt][3][r] + bias[3]) << 16);
      *(uint2*)&Xs[row][lrow * 4] = pk;   // col = jloc*4 + gate, gates packed
    }
  __syncthreads();
  int frow = tid >> 1, fh = tid & 1;
  int i = im * 128 + frow;
  int bb = i >> 8, tt = i & 255;
  size_t base = (((size_t)d * NT + tt) * NB + bb) * 1024 + (size_t)j0 * 4 + fh * 32;
#pragma unroll
  for (int q = 0; q < 4; ++q)
    *(uint4*)&X4[base + q * 8] = *(const uint4*)&Xs[frow][fh * 32 + q * 8];
}

// ---------------------------------------------------------------- lstm_scan
// (R8 structure — control; only change: H store is f16 u16, h32 dropped)
__global__ __launch_bounds__(1024, 4) void lstm_scan(const uint4* __restrict__ WT,
                                                     const ushort4* __restrict__ X4,
                                                     const float* __restrict__ h0,
                                                     const float* __restrict__ c0,
                                                     u16* __restrict__ H) {
  int d = blockIdx.x >> 6, b = blockIdx.x & 63;
  int tid = threadIdx.x;
  int jj = tid & 255, g = tid >> 8;
  __shared__ uint4 wlds[KK_SLAB * 256];
  __shared__ uint4 h2s4[32];
  __shared__ float4 plds[3][256];
  const uint4* Ws = WT + (size_t)d * 32768;
  for (int e = tid; e < KK_SLAB * 256; e += 1024) wlds[e] = Ws[e];
  uint4 wreg[KK_REG];
#pragma unroll
  for (int r = 0; r < KK_REG; ++r)
    wreg[r] = Ws[(size_t)(KK_SLAB + g * KK_REG + r) * 256 + jj];
  float c = 0.f;
  if (g == 0) c = c0[((size_t)d * NB + b) * 256 + jj];
  if (tid < 256) ((u16*)h2s4)[tid] = f2h(h0[((size_t)d * NB + b) * 256 + tid]);
  __syncthreads();
  for (int s = 0; s < NT; ++s) {
    int t = d ? (NT - 1 - s) : s;
    ushort4 xg = make_ushort4(0, 0, 0, 0);
    if (g == 0) xg = X4[(((size_t)d * NT + t) * NB + b) * 256 + jj];
    float ai = 0.f, af = 0.f, ag = 0.f, ao = 0.f;
    {
      uint4 hc0 = h2s4[24 + g * 2], hc1 = h2s4[24 + g * 2 + 1];
      unsigned int hp[8] = {hc0.x, hc0.y, hc0.z, hc0.w, hc1.x, hc1.y, hc1.z, hc1.w};
      const uint4* Wp_ = Ws + (size_t)(96 + g * 8) * 256 + jj;
#pragma unroll
      for (int u = 0; u < KK_STRM; ++u) {
        uint4 wv = Wp_[(size_t)u * 256];
        ai = dot2h(wv.x, hp[u], ai); af = dot2h(wv.y, hp[u], af);
        ag = dot2h(wv.z, hp[u], ag); ao = dot2h(wv.w, hp[u], ao);
      }
    }
    {
      uint4 ha0 = h2s4[g * 2], ha1 = h2s4[g * 2 + 1];
      unsigned int hp[8] = {ha0.x, ha0.y, ha0.z, ha0.w, ha1.x, ha1.y, ha1.z, ha1.w};
#pragma unroll
      for (int r = 0; r < 8; ++r) {
        uint4 wv = wlds[((g * 8 + r) << 8) | jj];
        ai = dot2h(wv.x, hp[r], ai); af = dot2h(wv.y, hp[r], af);
        ag = dot2h(wv.z, hp[r], ag); ao = dot2h(wv.w, hp[r], ao);
      }
    }
    {
      uint4 hb0 = h2s4[8 + g * 4], hb1 = h2s4[8 + g * 4 + 1];
      uint4 hb2 = h2s4[8 + g * 4 + 2], hb3 = h2s4[8 + g * 4 + 3];
      unsigned int hp[16] = {hb0.x, hb0.y, hb0.z, hb0.w, hb1.x, hb1.y, hb1.z, hb1.w,
                             hb2.x, hb2.y, hb2.z, hb2.w, hb3.x, hb3.y, hb3.z, hb3.w};
#pragma unroll
      for (int r = 0; r < KK_REG; ++r) {
        uint4 wv = wreg[r];
        ai = dot2h(wv.x, hp[r], ai); af = dot2h(wv.y, hp[r], af);
        ag = dot2h(wv.z, hp[r], ag); ao = dot2h(wv.w, hp[r], ao);
      }
    }
    if (g) plds[g - 1][jj] = make_float4(ai, af, ag, ao);
    __syncthreads();
    if (g == 0) {
      float4 p0 = plds[0][jj], p1 = plds[1][jj], p2 = plds[2][jj];
      ai += p0.x + p1.x + p2.x + b2f(xg.x);
      af += p0.y + p1.y + p2.y + b2f(xg.y);
      ag += p0.z + p1.z + p2.z + b2f(xg.z);
      ao += p0.w + p1.w + p2.w + b2f(xg.w);
      float ii = fsig(ai), ff = fsig(af), gg = ftanh(ag), oo = fsig(ao);
      c = ff * c + ii * gg;
      float h = oo * ftanh(c);
      u16 hu = f2h(h);
      ((u16*)h2s4)[jj] = hu;
      H[(((size_t)d * NB + b) * NT + t) * 256 + jj] = hu;
    }
    __syncthreads();
  }
}

// ---------------------------------------------------------------- feats
// feats[b][t][k] = [hf|hb] . Wp[k] + bp[k]; H is f16 u16, paired dot2.
__global__ __launch_bounds__(384) void feats_kernel(const u16* __restrict__ H,
                                                    const unsigned int* __restrict__ WpH,
                                                    const float* __restrict__ bp,
                                                    float* __restrict__ FT) {
  __shared__ uint4 hbuf[32][65];   // 32 rows x 512 h as 64 uint4 (+pad)
  __shared__ uint4 wbuf[64][12];   // WpH transposed: [it][k]
  int tid = threadIdx.x;
  int i0 = blockIdx.x * 32;
  for (int idx = tid; idx < 768; idx += 384) {
    int it = idx / 12, k = idx - it * 12;
    wbuf[it][k] = ((const uint4*)WpH)[k * 64 + it];
  }
  for (int idx = tid; idx < 2048; idx += 384) {
    int row = idx >> 6, c4 = idx & 63;
    int i = i0 + row;
    int b = i >> 8, t = i & 255;
    int dd = c4 >> 5, cc = c4 & 31;
    const uint4* hp = (const uint4*)(H + (((size_t)dd * NB + b) * NT + t) * 256);
    hbuf[row][c4] = hp[cc];
  }
  __syncthreads();
  int row = tid / 12, k = tid - row * 12;
  float s = 0.f;
#pragma unroll 8
  for (int it = 0; it < 64; ++it) {
    uint4 h4 = hbuf[row][it];
    uint4 w4 = wbuf[it][k];
    s = dot2h(h4.x, w4.x, s); s = dot2h(h4.y, w4.y, s);
    s = dot2h(h4.z, w4.z, s); s = dot2h(h4.w, w4.w, s);
  }
  int i = i0 + row;
  FT[(size_t)i * NKTAG + k] = s + bp[k];
}

// ---------------------------------------------------------------- viterbi
__global__ __launch_bounds__(64) void viterbi_kernel(const float* __restrict__ FT,
                                                     const float* __restrict__ trans,
                                                     const int* __restrict__ sent,
                                                     float* __restrict__ out) {
  int b = blockIdx.x, tid = threadIdx.x;
  __shared__ float trans_s[12][12];
  __shared__ float s_s[12];
  __shared__ unsigned char bp_s[256][12];
  __shared__ int path_s[256];
  for (int idx = tid; idx < 144; idx += 64) trans_s[idx / 12][idx % 12] = trans[idx];
  int cnt = 0;
#pragma unroll
  for (int q = 0; q < 4; ++q) cnt += (sent[b * NT + q * 64 + tid] > 0) ? 1 : 0;
  for (int off = 32; off; off >>= 1) cnt += __shfl_down(cnt, off);
  int len = __shfl(cnt, 0);
  if (tid < 12) s_s[tid] = (tid == START_TAG) ? 0.f : -10000.f;
  __syncthreads();
  for (int t = 0; t < NT; ++t) {
    float best = 0.f, f = 0.f;
    int barg = 0;
    if (tid < 12) {
      f = FT[((size_t)b * NT + t) * NKTAG + tid];
      best = s_s[0] + trans_s[tid][0];
      barg = 0;
#pragma unroll
      for (int fr = 1; fr < 12; ++fr) {
        float v = s_s[fr] + trans_s[tid][fr];
        if (v > best) { best = v; barg = fr; }  // strict > keeps first (jnp.argmax)
      }
    }
    __syncthreads();
    if (tid < 12) {
      s_s[tid] = best + f;
      bp_s[t][tid] = (unsigned char)barg;
    }
    __syncthreads();
  }
  if (tid == 0) {
    float bs = s_s[0];
    int bt = 0;
    for (int k = 1; k < 12; ++k)
      if (s_s[k] > bs) { bs = s_s[k]; bt = k; }
    out[NB * NT + b] = bs;  // best_score
    int x = bt;
    for (int tt = NT - 1; tt >= 0; --tt) {
      path_s[tt] = x;                  // emit BEFORE stepping back (ref semantics)
      int nxt = bp_s[tt][x];
      if (tt < len) x = nxt;
    }
  }
  __syncthreads();
#pragma unroll
  for (int q = 0; q < 4; ++q) {
    int t = q * 64 + tid;
    out[b * NT + t] = (t < len) ? (float)path_s[t] : -1.0f;
  }
}

// ---------------------------------------------------------------- launch
extern "C" void kernel_launch(void* const* d_in, const int* in_sizes, int n_in,
                              void* d_out, int out_size, void* d_ws, size_t ws_size,
                              hipStream_t stream) {
  (void)in_sizes; (void)n_in; (void)out_size; (void)ws_size;
  const int*   sent  = (const int*)d_in[0];
  const float* emb   = (const float*)d_in[2];
  const float* Wih_f = (const float*)d_in[3];
  const float* Whh_f = (const float*)d_in[4];
  const float* bih_f = (const float*)d_in[5];
  const float* bhh_f = (const float*)d_in[6];
  const float* Wih_b = (const float*)d_in[7];
  const float* Whh_b = (const float*)d_in[8];
  const float* bih_b = (const float*)d_in[9];
  const float* bhh_b = (const float*)d_in[10];
  const float* Wp    = (const float*)d_in[11];
  const float* bp    = (const float*)d_in[12];
  const float* trans = (const float*)d_in[13];
  const float* h0    = (const float*)d_in[14];
  const float* c0    = (const float*)d_in[15];
  float* out = (float*)d_out;

  char* w = (char*)d_ws;
  u16*   X4  = (u16*)w;                                      // 67108864 B
  uint4* WTH = (uint4*)(w + 67108864);                       //  1048576 B
  float* FT  = (float*)(w + 67108864 + 1048576);             //   786432 B
  unsigned int* WpH = (unsigned int*)(w + 68943872);         //    12288 B
  u16*   H   = (u16*)(w + 68956160);                         // 16777216 B

  pack_whh<<<dim3(257), dim3(256), 0, stream>>>(Whh_f, Whh_b, Wp, WTH, WpH);
  gemm_x<<<dim3(32, 128), dim3(256), 0, stream>>>(sent, emb, Wih_f, Wih_b,
                                                  bih_f, bhh_f, bih_b, bhh_b, X4);
  lstm_scan<<<dim3(128), dim3(1024), 0, stream>>>(WTH, (const ushort4*)X4, h0, c0, H);
  feats_kernel<<<dim3(512), dim3(384), 0, stream>>>(H, WpH, bp, FT);
  viterbi_kernel<<<dim3(64), dim3(64), 0, stream>>>(FT, trans, sent, out);
}